// Round 3
// baseline (451.643 us; speedup 1.0000x reference)
//
#include <hip/hip_runtime.h>

#define KCLS 19
#define NIMG 4
#define CCH  128
#define PPIX (256*512)   // 131072 pixels per image

// ---------------- workspace layout ----------------
// sums     [N][K][C]  float @ 0      (9728)  zeroed
// counts   [N][K]     float @ 9728   (76)    zeroed
// per_cls  [N][K]     float @ 9804   (76)    zeroed
// ticket   int        @ 9880         (1)     zeroed

// ---------- kernel 1: per-class feature sums + counts (fused) ----------
// block = (image n, channel pair, pixel half). Per-thread private LDS
// columns cols[k][tid] (float2): lane-exclusive accumulators, no atomics,
// b64 access at the free 2-way aliasing level. cg==0 blocks also histogram
// the labels (they tile every pixel exactly once).
__global__ __launch_bounds__(256) void k_sums(const float* __restrict__ predict,
                                              const int* __restrict__ target,
                                              float* __restrict__ sums,
                                              float* __restrict__ counts) {
  __shared__ float2 cols[KCLS*256];   // 38912 B
  __shared__ int lcnt[KCLS];
  const int tid = threadIdx.x;
  const int n    = blockIdx.x >> 7;
  const int rem  = blockIdx.x & 127;
  const int cg   = rem >> 1;
  const int half = rem & 1;
  const int c0   = cg * 2;
  const bool doCount = (cg == 0);

  for (int i = tid; i < KCLS*256; i += 256) cols[i] = make_float2(0.f, 0.f);
  if (tid < KCLS) lcnt[tid] = 0;
  __syncthreads();

  const float* p0 = predict + ((size_t)n*CCH + c0) * PPIX;
  const float* p1 = p0 + PPIX;
  const int*  lab = target + (size_t)n*PPIX;
  const int base0 = half * (PPIX/2);

  for (int off = tid*4; off < PPIX/2; off += 1024) {   // 64 iters
    const int base = base0 + off;
    const int4   lb = *(const int4*)(lab + base);
    const float4 a  = *(const float4*)(p0 + base);
    const float4 b  = *(const float4*)(p1 + base);
    const int   kk[4] = {lb.x, lb.y, lb.z, lb.w};
    const float av[4] = {a.x, a.y, a.z, a.w};
    const float bv[4] = {b.x, b.y, b.z, b.w};
#pragma unroll
    for (int j = 0; j < 4; ++j) {
      unsigned k = (unsigned)kk[j];
      if (k < KCLS) {
        float2* cp = &cols[k*256 + tid];
        cp->x += av[j];
        cp->y += bv[j];
        if (doCount) atomicAdd(&lcnt[k], 1);   // block-uniform branch
      }
    }
  }
  __syncthreads();
  // tree-reduce 256 columns x 19 classes; flat index -> all 8 waves busy
#pragma unroll
  for (int sh = 7; sh >= 0; --sh) {
    const int s = 1 << sh;
    for (int i = tid; i < KCLS*s; i += 256) {
      const int r   = i >> sh;
      const int col = i & (s - 1);
      float2* d = &cols[r*256 + col];
      const float2 o = cols[r*256 + col + s];
      d->x += o.x;
      d->y += o.y;
    }
    __syncthreads();
  }
  if (tid < KCLS) {
    atomicAdd(&sums[((size_t)n*KCLS + tid)*CCH + c0    ], cols[tid*256].x);
    atomicAdd(&sums[((size_t)n*KCLS + tid)*CCH + c0 + 1], cols[tid*256].y);
    if (doCount && lcnt[tid] > 0)
      atomicAdd(&counts[n*KCLS + tid], (float)lcnt[tid]);
  }
}

// ---------- kernel 2: loss_var pass + last-block final reduction ----------
// Each block computes its image's means inline from sums/counts (L2-hot),
// runs the per-pixel distance pass, accumulates per_cls, then the last
// block to finish computes loss_dis/loss_reg/loss_var and writes out[0].
__global__ __launch_bounds__(256) void k_var(const float* __restrict__ predict,
                                             const int* __restrict__ target,
                                             const float* __restrict__ sums,
                                             const float* __restrict__ counts,
                                             float* __restrict__ per_cls,
                                             int* __restrict__ ticket,
                                             float* __restrict__ out) {
  __shared__ float mT[CCH*20];        // [c][k] stride 20 -> conflict-free
  __shared__ float pc[KCLS];
  __shared__ bool  isLast;
  const int tid = threadIdx.x;
  const int n = blockIdx.x >> 7;
  const int tile = blockIdx.x & 127;

  // inline means for this image: m[k][c] = sums[n][k][c] / max(count,1)
  for (int i = tid; i < KCLS*CCH; i += 256) {
    const int k = i >> 7, c = i & 127;
    mT[c*20 + k] = sums[n*KCLS*CCH + i] / fmaxf(counts[n*KCLS + k], 1.f);
  }
  if (tid < KCLS) pc[tid] = 0.f;

  const int p0 = tile*1024 + tid*4;
  const int4 lb = *(const int4*)(target + (size_t)n*PPIX + p0);
  const unsigned u0 = min((unsigned)lb.x, (unsigned)(KCLS-1));
  const unsigned u1 = min((unsigned)lb.y, (unsigned)(KCLS-1));
  const unsigned u2 = min((unsigned)lb.z, (unsigned)(KCLS-1));
  const unsigned u3 = min((unsigned)lb.w, (unsigned)(KCLS-1));
  __syncthreads();

  float acc0 = 0.f, acc1 = 0.f, acc2 = 0.f, acc3 = 0.f;
  const float* gp = predict + (size_t)n*CCH*PPIX + p0;
#pragma unroll 8
  for (int c = 0; c < CCH; ++c) {
    const float4 v = *(const float4*)gp;
    gp += PPIX;
    const float* row = mT + c*20;
    const float d0 = row[u0] - v.x; acc0 = fmaf(d0, d0, acc0);
    const float d1 = row[u1] - v.y; acc1 = fmaf(d1, d1, acc1);
    const float d2 = row[u2] - v.z; acc2 = fmaf(d2, d2, acc2);
    const float d3 = row[u3] - v.w; acc3 = fmaf(d3, d3, acc3);
  }
  {
    float t;
    t = fmaxf(sqrtf(acc0) - 0.5f, 0.f); if ((unsigned)lb.x < KCLS) atomicAdd(&pc[lb.x], t*t);
    t = fmaxf(sqrtf(acc1) - 0.5f, 0.f); if ((unsigned)lb.y < KCLS) atomicAdd(&pc[lb.y], t*t);
    t = fmaxf(sqrtf(acc2) - 0.5f, 0.f); if ((unsigned)lb.z < KCLS) atomicAdd(&pc[lb.z], t*t);
    t = fmaxf(sqrtf(acc3) - 0.5f, 0.f); if ((unsigned)lb.w < KCLS) atomicAdd(&pc[lb.w], t*t);
  }
  __syncthreads();
  if (tid < KCLS) atomicAdd(&per_cls[n*KCLS + tid], pc[tid]);

  // ---- last-block finalize ----
  // __syncthreads drains vmcnt(0): this block's device-scope atomics have
  // reached the coherent point before the ticket increment below.
  __syncthreads();
  if (tid == 0) {
    __threadfence();
    const int old = atomicAdd(ticket, 1);
    isLast = (old == (int)gridDim.x - 1);
  }
  __syncthreads();
  if (!isLast) return;
  __threadfence();

  __shared__ float ml4[NIMG*KCLS*129];   // padded means, all images (39216 B)
  __shared__ float pcA[NIMG*KCLS];
  __shared__ float svalA[NIMG*KCLS];
  __shared__ float nvA[NIMG];
  __shared__ float red[256];

  for (int i = tid; i < NIMG*KCLS*CCH; i += 256) {
    const int nk = i >> 7;               // n*K + k
    const int c  = i & 127;
    ml4[nk*129 + c] = sums[i] / fmaxf(counts[nk], 1.f);
  }
  if (tid < NIMG*KCLS) {
    pcA[tid]   = atomicAdd(&per_cls[tid], 0.f);   // coherent read
    svalA[tid] = (counts[tid] > 20.f) ? 1.f : 0.f;
  }
  __syncthreads();
  if (tid < NIMG) {
    float s = 0.f;
    for (int k = 0; k < KCLS; ++k) s += svalA[tid*KCLS + k];
    nvA[tid] = fmaxf(s, 1.f);
  }
  __syncthreads();

  float local = 0.f;
  // loss_dis: ordered pairs f != s, both valid, per image
  for (int pr = tid; pr < NIMG*KCLS*KCLS; pr += 256) {
    const int n2 = pr / (KCLS*KCLS);
    const int r2 = pr % (KCLS*KCLS);
    const int f = r2 / KCLS, s2 = r2 % KCLS;
    if (f != s2 && svalA[n2*KCLS + f] > 0.f && svalA[n2*KCLS + s2] > 0.f) {
      const float* mf = ml4 + (n2*KCLS + f)*129;
      const float* ms = ml4 + (n2*KCLS + s2)*129;
      float acc = 0.f;
      for (int c = 0; c < CCH; ++c) {
        const float d = mf[c] - ms[c];
        acc = fmaf(d, d, acc);
      }
      const float t = fmaxf(3.0f - sqrtf(acc), 0.f);   // 2*DELTA = 3
      const float nv = nvA[n2];
      local += t * t / fmaxf(nv*(nv - 1.f), 1.f);
    }
  }
  // loss_reg + loss_var terms (one item per (n,k))
  if (tid < NIMG*KCLS) {
    const float nv = nvA[tid / KCLS];
    if (svalA[tid] > 0.f) {
      const float* m = ml4 + tid*129;
      float acc = 0.f;
      for (int c = 0; c < CCH; ++c) acc = fmaf(m[c], m[c], acc);
      local += 0.001f * sqrtf(acc) / nv;
      local += (pcA[tid] / fmaxf(counts[tid], 1.f)) / nv;
    }
  }
  red[tid] = local;
  __syncthreads();
  for (int s3 = 128; s3 >= 1; s3 >>= 1) {
    if (tid < s3) red[tid] += red[tid + s3];
    __syncthreads();
  }
  if (tid == 0) out[0] = 0.25f * red[0];   // mean over NIMG=4
}

extern "C" void kernel_launch(void* const* d_in, const int* in_sizes, int n_in,
                              void* d_out, int out_size, void* d_ws, size_t ws_size,
                              hipStream_t stream) {
  const float* predict = (const float*)d_in[0];
  const int*   target  = (const int*)d_in[1];
  float* out = (float*)d_out;
  float* ws  = (float*)d_ws;

  float* sums    = ws;            // 9728
  float* counts  = ws + 9728;     // 76
  float* per_cls = ws + 9804;     // 76
  int*   ticket  = (int*)(ws + 9880);

  // zero accumulators + ticket; ws is poisoned 0xAA
  hipMemsetAsync(ws, 0, (size_t)9884 * sizeof(float), stream);

  k_sums<<<NIMG*128, 256, 0, stream>>>(predict, target, sums, counts);
  k_var <<<NIMG*128, 256, 0, stream>>>(predict, target, sums, counts,
                                       per_cls, ticket, out);
}

// Round 4
// 449.426 us; speedup vs baseline: 1.0049x; 1.0049x over previous
//
#include <hip/hip_runtime.h>

#define KCLS 19
#define NIMG 4
#define CCH  128
#define PPIX (256*512)   // 131072 pixels per image

// ---------------- workspace layout ----------------
// sums     [N][K][C]  float @ 0      (9728)  zeroed
// counts   [N][K]     float @ 9728   (76)    zeroed
// per_cls  [N][K]     float @ 9804   (76)    zeroed
// ticket   int        @ 9880         (1)     zeroed

// ---------- kernel 1: per-class feature sums + counts (fused) ----------
// block = (image n, channel pair, pixel half). Per-thread private LDS
// columns cols[k][tid] (float2): lane-exclusive accumulators, no atomics,
// b64 access at the free 2-way aliasing level. cg==0 blocks also histogram
// the labels (they tile every pixel exactly once).
__global__ __launch_bounds__(256) void k_sums(const float* __restrict__ predict,
                                              const int* __restrict__ target,
                                              float* __restrict__ sums,
                                              float* __restrict__ counts) {
  __shared__ float2 cols[KCLS*256];   // 38912 B
  __shared__ int lcnt[KCLS];
  const int tid = threadIdx.x;
  const int n    = blockIdx.x >> 7;
  const int rem  = blockIdx.x & 127;
  const int cg   = rem >> 1;
  const int half = rem & 1;
  const int c0   = cg * 2;
  const bool doCount = (cg == 0);

  for (int i = tid; i < KCLS*256; i += 256) cols[i] = make_float2(0.f, 0.f);
  if (tid < KCLS) lcnt[tid] = 0;
  __syncthreads();

  const float* p0 = predict + ((size_t)n*CCH + c0) * PPIX;
  const float* p1 = p0 + PPIX;
  const int*  lab = target + (size_t)n*PPIX;
  const int base0 = half * (PPIX/2);

  for (int off = tid*4; off < PPIX/2; off += 1024) {   // 64 iters
    const int base = base0 + off;
    const int4   lb = *(const int4*)(lab + base);
    const float4 a  = *(const float4*)(p0 + base);
    const float4 b  = *(const float4*)(p1 + base);
    const int   kk[4] = {lb.x, lb.y, lb.z, lb.w};
    const float av[4] = {a.x, a.y, a.z, a.w};
    const float bv[4] = {b.x, b.y, b.z, b.w};
#pragma unroll
    for (int j = 0; j < 4; ++j) {
      unsigned k = (unsigned)kk[j];
      if (k < KCLS) {
        float2* cp = &cols[k*256 + tid];
        cp->x += av[j];
        cp->y += bv[j];
        if (doCount) atomicAdd(&lcnt[k], 1);   // block-uniform branch
      }
    }
  }
  __syncthreads();
  // tree-reduce 256 columns x 19 classes; flat index -> all 8 waves busy
#pragma unroll
  for (int sh = 7; sh >= 0; --sh) {
    const int s = 1 << sh;
    for (int i = tid; i < KCLS*s; i += 256) {
      const int r   = i >> sh;
      const int col = i & (s - 1);
      float2* d = &cols[r*256 + col];
      const float2 o = cols[r*256 + col + s];
      d->x += o.x;
      d->y += o.y;
    }
    __syncthreads();
  }
  if (tid < KCLS) {
    atomicAdd(&sums[((size_t)n*KCLS + tid)*CCH + c0    ], cols[tid*256].x);
    atomicAdd(&sums[((size_t)n*KCLS + tid)*CCH + c0 + 1], cols[tid*256].y);
    if (doCount && lcnt[tid] > 0)
      atomicAdd(&counts[n*KCLS + tid], (float)lcnt[tid]);
  }
}

// ---------- kernel 2: loss_var pass + last-block final reduction ----------
// No __threadfence anywhere: per_cls/ticket/readback are all device-scope
// atomics at the common coherence point; __syncthreads' vmcnt(0) drain
// orders per_cls commits before the ticket increment.
// Finalize reuses mT (2560 floats >= 19*129=2451), looping per image,
// so total LDS stays ~11.6 KB.
__global__ __launch_bounds__(256) void k_var(const float* __restrict__ predict,
                                             const int* __restrict__ target,
                                             const float* __restrict__ sums,
                                             const float* __restrict__ counts,
                                             float* __restrict__ per_cls,
                                             int* __restrict__ ticket,
                                             float* __restrict__ out) {
  __shared__ float mT[CCH*20];        // main: [c][k] stride 20; finalize: [k][c] stride 129
  __shared__ float pc[KCLS];
  __shared__ float sval[KCLS];
  __shared__ float pcs[NIMG*KCLS];
  __shared__ float red[256];
  __shared__ bool  isLast;
  const int tid = threadIdx.x;
  const int n = blockIdx.x >> 7;
  const int tile = blockIdx.x & 127;

  // inline means for this image: m[k][c] = sums[n][k][c] / max(count,1)
  for (int i = tid; i < KCLS*CCH; i += 256) {
    const int k = i >> 7, c = i & 127;
    mT[c*20 + k] = sums[n*KCLS*CCH + i] / fmaxf(counts[n*KCLS + k], 1.f);
  }
  if (tid < KCLS) pc[tid] = 0.f;

  const int p0 = tile*1024 + tid*4;
  const int4 lb = *(const int4*)(target + (size_t)n*PPIX + p0);
  const unsigned u0 = min((unsigned)lb.x, (unsigned)(KCLS-1));
  const unsigned u1 = min((unsigned)lb.y, (unsigned)(KCLS-1));
  const unsigned u2 = min((unsigned)lb.z, (unsigned)(KCLS-1));
  const unsigned u3 = min((unsigned)lb.w, (unsigned)(KCLS-1));
  __syncthreads();

  float acc0 = 0.f, acc1 = 0.f, acc2 = 0.f, acc3 = 0.f;
  const float* gp = predict + (size_t)n*CCH*PPIX + p0;
#pragma unroll 8
  for (int c = 0; c < CCH; ++c) {
    const float4 v = *(const float4*)gp;
    gp += PPIX;
    const float* row = mT + c*20;
    const float d0 = row[u0] - v.x; acc0 = fmaf(d0, d0, acc0);
    const float d1 = row[u1] - v.y; acc1 = fmaf(d1, d1, acc1);
    const float d2 = row[u2] - v.z; acc2 = fmaf(d2, d2, acc2);
    const float d3 = row[u3] - v.w; acc3 = fmaf(d3, d3, acc3);
  }
  {
    float t;
    t = fmaxf(sqrtf(acc0) - 0.5f, 0.f); if ((unsigned)lb.x < KCLS) atomicAdd(&pc[lb.x], t*t);
    t = fmaxf(sqrtf(acc1) - 0.5f, 0.f); if ((unsigned)lb.y < KCLS) atomicAdd(&pc[lb.y], t*t);
    t = fmaxf(sqrtf(acc2) - 0.5f, 0.f); if ((unsigned)lb.z < KCLS) atomicAdd(&pc[lb.z], t*t);
    t = fmaxf(sqrtf(acc3) - 0.5f, 0.f); if ((unsigned)lb.w < KCLS) atomicAdd(&pc[lb.w], t*t);
  }
  __syncthreads();
  if (tid < KCLS) atomicAdd(&per_cls[n*KCLS + tid], pc[tid]);

  // ---- ticket: last block to finish runs the finalize ----
  __syncthreads();   // vmcnt(0) drain: per_cls atomics committed
  if (tid == 0) {
    const int old = atomicAdd(ticket, 1);
    isLast = (old == (int)gridDim.x - 1);
  }
  __syncthreads();
  if (!isLast) return;

  // coherent readback of all per_cls accumulators (atomic-to-atomic chain)
  if (tid < NIMG*KCLS) pcs[tid] = atomicAdd(&per_cls[tid], 0.f);

  float local = 0.f;
  for (int n2 = 0; n2 < NIMG; ++n2) {
    // stage this image's means as [k][c] stride 129 (conflict-free)
    for (int i = tid; i < KCLS*CCH; i += 256) {
      const int k = i >> 7, c = i & 127;
      mT[k*129 + c] = sums[n2*KCLS*CCH + i] / fmaxf(counts[n2*KCLS + k], 1.f);
    }
    if (tid < KCLS) sval[tid] = (counts[n2*KCLS + tid] > 20.f) ? 1.f : 0.f;
    __syncthreads();

    float s = 0.f;
    for (int k = 0; k < KCLS; ++k) s += sval[k];
    const float nv = fmaxf(s, 1.f);

    // loss_dis: ordered pairs f != s2, both valid
    for (int pr = tid; pr < KCLS*KCLS; pr += 256) {
      const int f = pr / KCLS, s2 = pr % KCLS;
      if (f != s2 && sval[f] > 0.f && sval[s2] > 0.f) {
        const float* mf = mT + f*129;
        const float* ms = mT + s2*129;
        float acc = 0.f;
        for (int c = 0; c < CCH; ++c) {
          const float d = mf[c] - ms[c];
          acc = fmaf(d, d, acc);
        }
        const float t = fmaxf(3.0f - sqrtf(acc), 0.f);   // 2*DELTA = 3
        local += t * t / fmaxf(nv*(nv - 1.f), 1.f);
      }
    }
    // loss_reg + loss_var terms
    if (tid < KCLS && sval[tid] > 0.f) {
      const float* m = mT + tid*129;
      float acc = 0.f;
      for (int c = 0; c < CCH; ++c) acc = fmaf(m[c], m[c], acc);
      local += 0.001f * sqrtf(acc) / nv;
      local += (pcs[n2*KCLS + tid] / fmaxf(counts[n2*KCLS + tid], 1.f)) / nv;
    }
    __syncthreads();   // done reading mT/sval before next image overwrites
  }

  red[tid] = local;
  __syncthreads();
  for (int s3 = 128; s3 >= 1; s3 >>= 1) {
    if (tid < s3) red[tid] += red[tid + s3];
    __syncthreads();
  }
  if (tid == 0) out[0] = 0.25f * red[0];   // mean over NIMG=4
}

extern "C" void kernel_launch(void* const* d_in, const int* in_sizes, int n_in,
                              void* d_out, int out_size, void* d_ws, size_t ws_size,
                              hipStream_t stream) {
  const float* predict = (const float*)d_in[0];
  const int*   target  = (const int*)d_in[1];
  float* out = (float*)d_out;
  float* ws  = (float*)d_ws;

  float* sums    = ws;            // 9728
  float* counts  = ws + 9728;     // 76
  float* per_cls = ws + 9804;     // 76
  int*   ticket  = (int*)(ws + 9880);

  // zero accumulators + ticket; ws is poisoned 0xAA
  hipMemsetAsync(ws, 0, (size_t)9884 * sizeof(float), stream);

  k_sums<<<NIMG*128, 256, 0, stream>>>(predict, target, sums, counts);
  k_var <<<NIMG*128, 256, 0, stream>>>(predict, target, sums, counts,
                                       per_cls, ticket, out);
}

// Round 5
// 430.763 us; speedup vs baseline: 1.0485x; 1.0433x over previous
//
#include <hip/hip_runtime.h>

#define KCLS 19
#define NIMG 4
#define CCH  128
#define PPIX (256*512)   // 131072 pixels per image

// ---------------- workspace layout ----------------
// sums     [N][K][C]  float @ 0      (9728)  zeroed
// counts   [N][K]     float @ 9728   (76)    zeroed
// per_cls  [N][K]     float @ 9804   (76)    zeroed

// ---------- kernel 1: per-class feature sums + counts (fused) ----------
// block = (image n, channel pair, pixel half). Per-thread private LDS
// columns cols[k][tid] (float2): lane-exclusive accumulators, no atomics,
// b64 access at the free 2-way aliasing level. cg==0 blocks also histogram
// the labels (they tile every pixel exactly once).
__global__ __launch_bounds__(256) void k_sums(const float* __restrict__ predict,
                                              const int* __restrict__ target,
                                              float* __restrict__ sums,
                                              float* __restrict__ counts) {
  __shared__ float2 cols[KCLS*256];   // 38912 B
  __shared__ int lcnt[KCLS];
  const int tid = threadIdx.x;
  const int n    = blockIdx.x >> 7;
  const int rem  = blockIdx.x & 127;
  const int cg   = rem >> 1;
  const int half = rem & 1;
  const int c0   = cg * 2;
  const bool doCount = (cg == 0);

  for (int i = tid; i < KCLS*256; i += 256) cols[i] = make_float2(0.f, 0.f);
  if (tid < KCLS) lcnt[tid] = 0;
  __syncthreads();

  const float* p0 = predict + ((size_t)n*CCH + c0) * PPIX;
  const float* p1 = p0 + PPIX;
  const int*  lab = target + (size_t)n*PPIX;
  const int base0 = half * (PPIX/2);

  for (int off = tid*4; off < PPIX/2; off += 1024) {   // 64 iters
    const int base = base0 + off;
    const int4   lb = *(const int4*)(lab + base);
    const float4 a  = *(const float4*)(p0 + base);
    const float4 b  = *(const float4*)(p1 + base);
    const int   kk[4] = {lb.x, lb.y, lb.z, lb.w};
    const float av[4] = {a.x, a.y, a.z, a.w};
    const float bv[4] = {b.x, b.y, b.z, b.w};
#pragma unroll
    for (int j = 0; j < 4; ++j) {
      unsigned k = (unsigned)kk[j];
      if (k < KCLS) {
        float2* cp = &cols[k*256 + tid];
        cp->x += av[j];
        cp->y += bv[j];
        if (doCount) atomicAdd(&lcnt[k], 1);   // block-uniform branch
      }
    }
  }
  __syncthreads();
  // tree-reduce 256 columns x 19 classes; flat index -> all 8 waves busy
#pragma unroll
  for (int sh = 7; sh >= 0; --sh) {
    const int s = 1 << sh;
    for (int i = tid; i < KCLS*s; i += 256) {
      const int r   = i >> sh;
      const int col = i & (s - 1);
      float2* d = &cols[r*256 + col];
      const float2 o = cols[r*256 + col + s];
      d->x += o.x;
      d->y += o.y;
    }
    __syncthreads();
  }
  if (tid < KCLS) {
    atomicAdd(&sums[((size_t)n*KCLS + tid)*CCH + c0    ], cols[tid*256].x);
    atomicAdd(&sums[((size_t)n*KCLS + tid)*CCH + c0 + 1], cols[tid*256].y);
    if (doCount && lcnt[tid] > 0)
      atomicAdd(&counts[n*KCLS + tid], (float)lcnt[tid]);
  }
}

// ---------- kernel 2: loss_var pass (lean — no finalize) ----------
// Inline means from sums/counts (L2-hot), streaming distance pass,
// per_cls accumulation. Minimal LDS/VGPR footprint for occupancy.
__global__ __launch_bounds__(256) void k_var(const float* __restrict__ predict,
                                             const int* __restrict__ target,
                                             const float* __restrict__ sums,
                                             const float* __restrict__ counts,
                                             float* __restrict__ per_cls) {
  __shared__ float mT[CCH*20];        // [c][k] stride 20 -> conflict-free
  __shared__ float pc[KCLS];
  const int tid = threadIdx.x;
  const int n = blockIdx.x >> 7;
  const int tile = blockIdx.x & 127;

  // inline means for this image: m[k][c] = sums[n][k][c] / max(count,1)
  for (int i = tid; i < KCLS*CCH; i += 256) {
    const int k = i >> 7, c = i & 127;
    mT[c*20 + k] = sums[n*KCLS*CCH + i] / fmaxf(counts[n*KCLS + k], 1.f);
  }
  if (tid < KCLS) pc[tid] = 0.f;

  const int p0 = tile*1024 + tid*4;
  const int4 lb = *(const int4*)(target + (size_t)n*PPIX + p0);
  const unsigned u0 = min((unsigned)lb.x, (unsigned)(KCLS-1));
  const unsigned u1 = min((unsigned)lb.y, (unsigned)(KCLS-1));
  const unsigned u2 = min((unsigned)lb.z, (unsigned)(KCLS-1));
  const unsigned u3 = min((unsigned)lb.w, (unsigned)(KCLS-1));
  __syncthreads();

  float acc0 = 0.f, acc1 = 0.f, acc2 = 0.f, acc3 = 0.f;
  const float* gp = predict + (size_t)n*CCH*PPIX + p0;
#pragma unroll 8
  for (int c = 0; c < CCH; ++c) {
    const float4 v = *(const float4*)gp;
    gp += PPIX;
    const float* row = mT + c*20;
    const float d0 = row[u0] - v.x; acc0 = fmaf(d0, d0, acc0);
    const float d1 = row[u1] - v.y; acc1 = fmaf(d1, d1, acc1);
    const float d2 = row[u2] - v.z; acc2 = fmaf(d2, d2, acc2);
    const float d3 = row[u3] - v.w; acc3 = fmaf(d3, d3, acc3);
  }
  {
    float t;
    t = fmaxf(sqrtf(acc0) - 0.5f, 0.f); if ((unsigned)lb.x < KCLS) atomicAdd(&pc[lb.x], t*t);
    t = fmaxf(sqrtf(acc1) - 0.5f, 0.f); if ((unsigned)lb.y < KCLS) atomicAdd(&pc[lb.y], t*t);
    t = fmaxf(sqrtf(acc2) - 0.5f, 0.f); if ((unsigned)lb.z < KCLS) atomicAdd(&pc[lb.z], t*t);
    t = fmaxf(sqrtf(acc3) - 0.5f, 0.f); if ((unsigned)lb.w < KCLS) atomicAdd(&pc[lb.w], t*t);
  }
  __syncthreads();
  if (tid < KCLS) atomicAdd(&per_cls[n*KCLS + tid], pc[tid]);
}

// ---------- kernel 3: per-image finalize (4 blocks, atomic into out) ----------
// One block per image: recompute means (tiny, L2-hot), loss_dis over the
// 361 ordered pairs, loss_reg, loss_var from per_cls/counts; atomicAdd
// 0.25 * per-image loss into the pre-zeroed out[0]. Cross-dispatch
// coherence makes plain loads of per_cls/sums/counts valid here.
__global__ __launch_bounds__(256) void k_final(const float* __restrict__ sums,
                                               const float* __restrict__ counts,
                                               const float* __restrict__ per_cls,
                                               float* __restrict__ out) {
  __shared__ float ml[KCLS*129];   // [k][c] stride 129 -> conflict-free
  __shared__ float sval[KCLS];
  __shared__ float red[256];
  const int tid = threadIdx.x;
  const int n = blockIdx.x;

  for (int i = tid; i < KCLS*CCH; i += 256) {
    const int k = i >> 7, c = i & 127;
    ml[k*129 + c] = sums[n*KCLS*CCH + i] / fmaxf(counts[n*KCLS + k], 1.f);
  }
  if (tid < KCLS) sval[tid] = (counts[n*KCLS + tid] > 20.f) ? 1.f : 0.f;
  __syncthreads();

  float s = 0.f;
  for (int k = 0; k < KCLS; ++k) s += sval[k];
  const float nv = fmaxf(s, 1.f);

  float local = 0.f;
  // loss_dis: ordered pairs f != s2, both valid
  for (int pr = tid; pr < KCLS*KCLS; pr += 256) {
    const int f = pr / KCLS, s2 = pr % KCLS;
    if (f != s2 && sval[f] > 0.f && sval[s2] > 0.f) {
      const float* mf = ml + f*129;
      const float* ms = ml + s2*129;
      float acc = 0.f;
      for (int c = 0; c < CCH; ++c) {
        const float d = mf[c] - ms[c];
        acc = fmaf(d, d, acc);
      }
      const float t = fmaxf(3.0f - sqrtf(acc), 0.f);   // 2*DELTA = 3
      local += t * t / fmaxf(nv*(nv - 1.f), 1.f);
    }
  }
  // loss_reg + loss_var terms
  if (tid < KCLS && sval[tid] > 0.f) {
    const float* m = ml + tid*129;
    float acc = 0.f;
    for (int c = 0; c < CCH; ++c) acc = fmaf(m[c], m[c], acc);
    local += 0.001f * sqrtf(acc) / nv;
    local += (per_cls[n*KCLS + tid] / fmaxf(counts[n*KCLS + tid], 1.f)) / nv;
  }

  red[tid] = local;
  __syncthreads();
  for (int s3 = 128; s3 >= 1; s3 >>= 1) {
    if (tid < s3) red[tid] += red[tid + s3];
    __syncthreads();
  }
  if (tid == 0) atomicAdd(out, 0.25f * red[0]);   // mean over NIMG=4
}

extern "C" void kernel_launch(void* const* d_in, const int* in_sizes, int n_in,
                              void* d_out, int out_size, void* d_ws, size_t ws_size,
                              hipStream_t stream) {
  const float* predict = (const float*)d_in[0];
  const int*   target  = (const int*)d_in[1];
  float* out = (float*)d_out;
  float* ws  = (float*)d_ws;

  float* sums    = ws;            // 9728
  float* counts  = ws + 9728;     // 76
  float* per_cls = ws + 9804;     // 76

  // zero accumulators (ws is poisoned 0xAA) and out (k_final accumulates)
  hipMemsetAsync(ws, 0, (size_t)9880 * sizeof(float), stream);
  hipMemsetAsync(out, 0, sizeof(float), stream);

  k_sums <<<NIMG*128, 256, 0, stream>>>(predict, target, sums, counts);
  k_var  <<<NIMG*128, 256, 0, stream>>>(predict, target, sums, counts, per_cls);
  k_final<<<NIMG, 256, 0, stream>>>(sums, counts, per_cls, out);
}